// Round 1
// baseline (1509.739 us; speedup 1.0000x reference)
//
#include <hip/hip_runtime.h>

#define HIDDEN 2048
#define QUANT  16
#define BATCH  8192
#define HALFD  1024

typedef _Float16 half8  __attribute__((ext_vector_type(8)));
typedef float    floatx4 __attribute__((ext_vector_type(4)));

__device__ __forceinline__ void load_lds16(const void* gptr, void* lptr) {
  __builtin_amdgcn_global_load_lds(
      (const __attribute__((address_space(1))) void*)gptr,
      (__attribute__((address_space(3))) void*)lptr, 16, 0, 0);
}

// ---- x fp32 -> fp16 ----
__global__ __launch_bounds__(256) void convert_x_kernel(const float* __restrict__ x,
                                                        _Float16* __restrict__ xh) {
  const int i = (blockIdx.x * 256 + threadIdx.x) * 8;
  const float4 a = *(const float4*)(x + i);
  const float4 b = *(const float4*)(x + i + 4);
  half8 h;
  h[0] = (_Float16)a.x; h[1] = (_Float16)a.y; h[2] = (_Float16)a.z; h[3] = (_Float16)a.w;
  h[4] = (_Float16)b.x; h[5] = (_Float16)b.y; h[6] = (_Float16)b.z; h[7] = (_Float16)b.w;
  *(half8*)(xh + i) = h;
}

// ---- W1 [Q][H][N] fp32 -> W1T [Q][N][H] fp16 (transpose so both GEMM operands are K-contiguous) ----
__global__ __launch_bounds__(256) void transpose_w1_kernel(const float* __restrict__ W1,
                                                           _Float16* __restrict__ W1T) {
  __shared__ float tile[32][33];
  const int q  = blockIdx.z;
  const int h0 = blockIdx.y * 32;
  const int n0 = blockIdx.x * 32;
  const float* src = W1 + (size_t)q * HIDDEN * HALFD;
  _Float16*    dst = W1T + (size_t)q * HALFD * HIDDEN;
  const int tx = threadIdx.x, ty = threadIdx.y;
  #pragma unroll
  for (int j = 0; j < 32; j += 8)
    tile[ty + j][tx] = src[(size_t)(h0 + ty + j) * HALFD + n0 + tx];
  __syncthreads();
  #pragma unroll
  for (int j = 0; j < 32; j += 8)
    dst[(size_t)(n0 + ty + j) * HIDDEN + h0 + tx] = (_Float16)tile[tx][ty + j];
}

// ---- out[b][q] = b2[q] (atomics accumulate on top) ----
__global__ __launch_bounds__(256) void init_out_kernel(float* __restrict__ out,
                                                       const float* __restrict__ b2) {
  const int i = blockIdx.x * 256 + threadIdx.x;
  out[i] = b2[i & (QUANT - 1)];
}

// ---- fused GEMM + bias + GELU + W2-reduction ----
// grid: (128, 64). blockIdx.x = n-tile (head q = x>>3, 128-col slab (x&7)), blockIdx.y = m-tile.
// 128x128 tile, BK=64, 4 waves in 2x2, each wave 4x4 frags of 16x16x32 f16 MFMA.
__global__ __launch_bounds__(256) void qhead_gemm_kernel(
    const _Float16* __restrict__ A,   // [BATCH][HIDDEN] fp16
    const _Float16* __restrict__ BT,  // [QUANT][HALFD][HIDDEN] fp16
    const float* __restrict__ b1,     // [QUANT][HALFD]
    const float* __restrict__ W2,     // [QUANT][HALFD]
    float* __restrict__ out) {        // [BATCH][QUANT]
  __shared__ _Float16 As[128 * 64];
  __shared__ _Float16 Bs[128 * 64];

  const int tid  = threadIdx.x;
  const int lane = tid & 63;
  const int wave = tid >> 6;
  const int wm = wave >> 1, wn = wave & 1;
  const int lrow = lane & 15, quad = lane >> 4;

  const int m0 = blockIdx.y << 7;
  const int q  = blockIdx.x >> 3;
  const int n0 = (blockIdx.x & 7) << 7;  // column base within head

  const _Float16* Ablk = A + (size_t)m0 * HIDDEN;
  const _Float16* Bblk = BT + ((size_t)q * HALFD + n0) * HIDDEN;

  // staging: chunk c = i*256+tid -> LDS bytes c*16 (wave-uniform base + lane*16).
  // XOR swizzle applied on the GLOBAL k-group so LDS stays DMA-contiguous:
  // LDS chunk (row r, group g) holds global k-group g^(r&7).
  const int row_t = tid >> 3;                       // row within 32-row slab
  const int gx = (((tid & 7) ^ (row_t & 7)) << 3);  // swizzled k element offset
  const _Float16* agp = Ablk + (size_t)row_t * HIDDEN + gx;
  const _Float16* bgp = Bblk + (size_t)row_t * HIDDEN + gx;
  _Float16* alp = &As[tid * 8];
  _Float16* blp = &Bs[tid * 8];

  int aoff[4], boff[4];
  #pragma unroll
  for (int f = 0; f < 4; ++f) {
    aoff[f] = (wm * 64 + f * 16 + lrow) * 64;
    boff[f] = (wn * 64 + f * 16 + lrow) * 64;
  }
  const int lxor = lrow & 7;

  floatx4 acc[4][4];
  #pragma unroll
  for (int mf = 0; mf < 4; ++mf)
    #pragma unroll
    for (int nf = 0; nf < 4; ++nf)
      acc[mf][nf] = (floatx4){0.f, 0.f, 0.f, 0.f};

  for (int kt = 0; kt < HIDDEN; kt += 64) {
    #pragma unroll
    for (int i = 0; i < 4; ++i)
      load_lds16(agp + (size_t)(i * 32) * HIDDEN + kt, alp + i * 2048);
    #pragma unroll
    for (int i = 0; i < 4; ++i)
      load_lds16(bgp + (size_t)(i * 32) * HIDDEN + kt, blp + i * 2048);
    __syncthreads();  // drains vmcnt: global_load_lds data visible

    #pragma unroll
    for (int ks = 0; ks < 2; ++ks) {
      const int kxo = ((((ks << 2) | quad) ^ lxor) << 3);
      half8 af[4], bf[4];
      #pragma unroll
      for (int mf = 0; mf < 4; ++mf) af[mf] = *(const half8*)&As[aoff[mf] + kxo];
      #pragma unroll
      for (int nf = 0; nf < 4; ++nf) bf[nf] = *(const half8*)&Bs[boff[nf] + kxo];
      #pragma unroll
      for (int mf = 0; mf < 4; ++mf)
        #pragma unroll
        for (int nf = 0; nf < 4; ++nf)
          acc[mf][nf] = __builtin_amdgcn_mfma_f32_16x16x32_f16(af[mf], bf[nf], acc[mf][nf], 0, 0, 0);
    }
    __syncthreads();  // all waves done reading before next tile overwrites LDS
  }

  // ---- epilogue: bias + exact GELU + *W2, reduce over this wave's 64 columns ----
  // C/D layout: col = lane&15, row = quad*4 + reg   [verified m89/m91]
  const int nbase = n0 + wn * 64;
  float rowsum[4][4];
  #pragma unroll
  for (int mf = 0; mf < 4; ++mf)
    #pragma unroll
    for (int i = 0; i < 4; ++i) rowsum[mf][i] = 0.f;

  #pragma unroll
  for (int nf = 0; nf < 4; ++nf) {
    const int ncol = nbase + nf * 16 + lrow;
    const float b1v = b1[q * HALFD + ncol];
    const float w2v = W2[q * HALFD + ncol];
    #pragma unroll
    for (int mf = 0; mf < 4; ++mf) {
      #pragma unroll
      for (int i = 0; i < 4; ++i) {
        const float v = acc[mf][nf][i] + b1v;
        const float g = 0.5f * v * (1.f + erff(v * 0.70710678118654752f));
        rowsum[mf][i] += g * w2v;
      }
    }
  }
  // butterfly-sum across the 16 column-lanes (low 4 lane bits)
  #pragma unroll
  for (int mf = 0; mf < 4; ++mf) {
    #pragma unroll
    for (int i = 0; i < 4; ++i) {
      float t = rowsum[mf][i];
      t += __shfl_xor(t, 1, 64);
      t += __shfl_xor(t, 2, 64);
      t += __shfl_xor(t, 4, 64);
      t += __shfl_xor(t, 8, 64);
      rowsum[mf][i] = t;
    }
  }
  if (lrow == 0) {
    #pragma unroll
    for (int mf = 0; mf < 4; ++mf) {
      const int mrow = (blockIdx.y << 7) + wm * 64 + mf * 16 + quad * 4;
      #pragma unroll
      for (int i = 0; i < 4; ++i)
        atomicAdd(&out[(size_t)(mrow + i) * QUANT + q], rowsum[mf][i]);
    }
  }
}

extern "C" void kernel_launch(void* const* d_in, const int* in_sizes, int n_in,
                              void* d_out, int out_size, void* d_ws, size_t ws_size,
                              hipStream_t stream) {
  const float* x  = (const float*)d_in[0];
  const float* W1 = (const float*)d_in[1];
  const float* b1 = (const float*)d_in[2];
  const float* W2 = (const float*)d_in[3];
  const float* b2 = (const float*)d_in[4];
  float* out = (float*)d_out;

  _Float16* xh  = (_Float16*)d_ws;                                   // 32 MB
  _Float16* w1t = (_Float16*)((char*)d_ws +
                  (size_t)BATCH * HIDDEN * sizeof(_Float16));        // 64 MB

  convert_x_kernel<<<BATCH * HIDDEN / (256 * 8), 256, 0, stream>>>(x, xh);
  transpose_w1_kernel<<<dim3(HALFD / 32, HIDDEN / 32, QUANT), dim3(32, 8), 0, stream>>>(W1, w1t);
  init_out_kernel<<<BATCH * QUANT / 256, 256, 0, stream>>>(out, b2);
  qhead_gemm_kernel<<<dim3(128, 64), 256, 0, stream>>>(xh, w1t, b1, W2, out);
}

// Round 2
// 1064.036 us; speedup vs baseline: 1.4189x; 1.4189x over previous
//
#include <hip/hip_runtime.h>

#define HIDDEN 2048
#define QUANT  16
#define BATCH  8192
#define HALFD  1024

typedef _Float16 half8  __attribute__((ext_vector_type(8)));
typedef _Float16 half4  __attribute__((ext_vector_type(4)));
typedef float    floatx4 __attribute__((ext_vector_type(4)));

__device__ __forceinline__ void load_lds16(const void* gptr, void* lptr) {
  __builtin_amdgcn_global_load_lds(
      (const __attribute__((address_space(1))) void*)gptr,
      (__attribute__((address_space(3))) void*)lptr, 16, 0, 0);
}

// exact-GELU via Abramowitz-Stegun 7.1.26 erf (|eps_erf| <= 1.5e-7)
__device__ __forceinline__ float gelu_exact(float v) {
  const float z  = 0.7071067811865476f * v;
  const float az = fabsf(z);
  const float t  = __builtin_amdgcn_rcpf(1.0f + 0.3275911f * az);
  const float p  = t * (0.254829592f +
                   t * (-0.284496736f +
                   t * (1.421413741f +
                   t * (-1.453152027f +
                   t * 1.061405429f))));
  float er = 1.0f - p * __expf(-az * az);
  er = copysignf(er, z);
  return 0.5f * v * (1.0f + er);
}

// ---- x fp32 -> fp16 ----
__global__ __launch_bounds__(256) void convert_x_kernel(const float* __restrict__ x,
                                                        _Float16* __restrict__ xh) {
  const int i = (blockIdx.x * 256 + threadIdx.x) * 8;
  const float4 a = *(const float4*)(x + i);
  const float4 b = *(const float4*)(x + i + 4);
  half8 h;
  h[0] = (_Float16)a.x; h[1] = (_Float16)a.y; h[2] = (_Float16)a.z; h[3] = (_Float16)a.w;
  h[4] = (_Float16)b.x; h[5] = (_Float16)b.y; h[6] = (_Float16)b.z; h[7] = (_Float16)b.w;
  *(half8*)(xh + i) = h;
}

// ---- W1 [Q][H][N] fp32 -> W1T [Q][N][H] fp16 ----
__global__ __launch_bounds__(256) void transpose_w1_kernel(const float* __restrict__ W1,
                                                           _Float16* __restrict__ W1T) {
  __shared__ float tile[32][33];
  const int q  = blockIdx.z;
  const int h0 = blockIdx.y * 32;
  const int n0 = blockIdx.x * 32;
  const float* src = W1 + (size_t)q * HIDDEN * HALFD;
  _Float16*    dst = W1T + (size_t)q * HALFD * HIDDEN;
  const int t = threadIdx.x;
  const int lx = t & 31, ly = t >> 5;  // load: 32 cols x 8 rows, x4 row-strided
  #pragma unroll
  for (int j = 0; j < 4; ++j)
    tile[ly + 8 * j][lx] = src[(size_t)(h0 + ly + 8 * j) * HALFD + n0 + lx];
  __syncthreads();
  const int wy = t >> 3, wx = t & 7;   // store: row n0+wy, 4 h-contiguous halves
  half4 v;
  #pragma unroll
  for (int c = 0; c < 4; ++c) v[c] = (_Float16)tile[wx * 4 + c][wy];
  *(half4*)(dst + (size_t)(n0 + wy) * HIDDEN + h0 + wx * 4) = v;
}

// ---- out[b][q] = b2[q] (atomics accumulate on top) ----
__global__ __launch_bounds__(256) void init_out_kernel(float* __restrict__ out,
                                                       const float* __restrict__ b2) {
  const int i = blockIdx.x * 256 + threadIdx.x;
  out[i] = b2[i & (QUANT - 1)];
}

// ---- fused GEMM + bias + GELU + W2-reduction ----
// Tile 64(m) x 128(n), BK=64. 4 waves in 2x2; each wave 2x4 frags of 16x16x32 f16.
// Small acc (32 regs/wave) -> ~5 waves/SIMD occupancy; LDS 24 KB -> 6 blocks cap.
__global__ __launch_bounds__(256, 4) void qhead_gemm_kernel(
    const _Float16* __restrict__ A,   // [BATCH][HIDDEN] fp16
    const _Float16* __restrict__ BT,  // [QUANT][HALFD][HIDDEN] fp16
    const float* __restrict__ b1,     // [QUANT][HALFD]
    const float* __restrict__ W2,     // [QUANT][HALFD]
    float* __restrict__ out) {        // [BATCH][QUANT]
  __shared__ _Float16 As[64 * 64];    // 8 KB
  __shared__ _Float16 Bs[128 * 64];   // 16 KB

  const int tid  = threadIdx.x;
  const int lane = tid & 63;
  const int wave = tid >> 6;
  const int wm = wave >> 1, wn = wave & 1;
  const int lrow = lane & 15, quad = lane >> 4;

  const int m0 = blockIdx.y << 6;
  const int q  = blockIdx.x >> 3;
  const int n0 = (blockIdx.x & 7) << 7;  // column base within head

  const _Float16* Ablk = A + (size_t)m0 * HIDDEN;
  const _Float16* Bblk = BT + ((size_t)q * HALFD + n0) * HIDDEN;

  // staging: chunk c -> LDS bytes c*16 (wave-uniform base + lane*16).
  // XOR swizzle on the GLOBAL k-group: LDS chunk (row r, group g) holds
  // global k-group g^(r&7); rows strided by 32 share (r&7).
  const int row_t = tid >> 3;
  const int gx = (((tid & 7) ^ (row_t & 7)) << 3);
  const _Float16* agp = Ablk + (size_t)row_t * HIDDEN + gx;
  const _Float16* bgp = Bblk + (size_t)row_t * HIDDEN + gx;
  _Float16* alp = &As[tid * 8];
  _Float16* blp = &Bs[tid * 8];

  int aoff[2], boff[4];
  #pragma unroll
  for (int f = 0; f < 2; ++f) aoff[f] = (wm * 32 + f * 16 + lrow) * 64;
  #pragma unroll
  for (int f = 0; f < 4; ++f) boff[f] = (wn * 64 + f * 16 + lrow) * 64;
  const int lxor = lrow & 7;

  floatx4 acc[2][4];
  #pragma unroll
  for (int mf = 0; mf < 2; ++mf)
    #pragma unroll
    for (int nf = 0; nf < 4; ++nf)
      acc[mf][nf] = (floatx4){0.f, 0.f, 0.f, 0.f};

  for (int kt = 0; kt < HIDDEN; kt += 64) {
    #pragma unroll
    for (int i = 0; i < 2; ++i)
      load_lds16(agp + (size_t)(i * 32) * HIDDEN + kt, alp + i * 2048);
    #pragma unroll
    for (int i = 0; i < 4; ++i)
      load_lds16(bgp + (size_t)(i * 32) * HIDDEN + kt, blp + i * 2048);
    __syncthreads();

    #pragma unroll
    for (int ks = 0; ks < 2; ++ks) {
      const int kxo = ((((ks << 2) | quad) ^ lxor) << 3);
      half8 af[2], bf[4];
      #pragma unroll
      for (int mf = 0; mf < 2; ++mf) af[mf] = *(const half8*)&As[aoff[mf] + kxo];
      #pragma unroll
      for (int nf = 0; nf < 4; ++nf) bf[nf] = *(const half8*)&Bs[boff[nf] + kxo];
      #pragma unroll
      for (int mf = 0; mf < 2; ++mf)
        #pragma unroll
        for (int nf = 0; nf < 4; ++nf)
          acc[mf][nf] = __builtin_amdgcn_mfma_f32_16x16x32_f16(af[mf], bf[nf], acc[mf][nf], 0, 0, 0);
    }
    __syncthreads();
  }

  // ---- epilogue: bias + exact GELU + *W2, reduce over this wave's 64 columns ----
  // C/D layout: col = lane&15, row = quad*4 + reg   [verified m89/m91]
  const int nbase = n0 + wn * 64;
  float rowsum[2][4];
  #pragma unroll
  for (int mf = 0; mf < 2; ++mf)
    #pragma unroll
    for (int i = 0; i < 4; ++i) rowsum[mf][i] = 0.f;

  #pragma unroll
  for (int nf = 0; nf < 4; ++nf) {
    const int ncol = nbase + nf * 16 + lrow;
    const float b1v = b1[q * HALFD + ncol];
    const float w2v = W2[q * HALFD + ncol];
    #pragma unroll
    for (int mf = 0; mf < 2; ++mf) {
      #pragma unroll
      for (int i = 0; i < 4; ++i) {
        rowsum[mf][i] += gelu_exact(acc[mf][nf][i] + b1v) * w2v;
      }
    }
  }
  // butterfly-sum across the 16 column-lanes (low 4 lane bits)
  #pragma unroll
  for (int mf = 0; mf < 2; ++mf) {
    #pragma unroll
    for (int i = 0; i < 4; ++i) {
      float t = rowsum[mf][i];
      t += __shfl_xor(t, 1, 64);
      t += __shfl_xor(t, 2, 64);
      t += __shfl_xor(t, 4, 64);
      t += __shfl_xor(t, 8, 64);
      rowsum[mf][i] = t;
    }
  }
  if (lrow == 0) {
    #pragma unroll
    for (int mf = 0; mf < 2; ++mf) {
      const int mrow = m0 + wm * 32 + mf * 16 + quad * 4;
      #pragma unroll
      for (int i = 0; i < 4; ++i)
        atomicAdd(&out[(size_t)(mrow + i) * QUANT + q], rowsum[mf][i]);
    }
  }
}

extern "C" void kernel_launch(void* const* d_in, const int* in_sizes, int n_in,
                              void* d_out, int out_size, void* d_ws, size_t ws_size,
                              hipStream_t stream) {
  const float* x  = (const float*)d_in[0];
  const float* W1 = (const float*)d_in[1];
  const float* b1 = (const float*)d_in[2];
  const float* W2 = (const float*)d_in[3];
  const float* b2 = (const float*)d_in[4];
  float* out = (float*)d_out;

  _Float16* xh  = (_Float16*)d_ws;                                   // 32 MB
  _Float16* w1t = (_Float16*)((char*)d_ws +
                  (size_t)BATCH * HIDDEN * sizeof(_Float16));        // 64 MB

  convert_x_kernel<<<BATCH * HIDDEN / (256 * 8), 256, 0, stream>>>(x, xh);
  transpose_w1_kernel<<<dim3(HALFD / 32, HIDDEN / 32, QUANT), 256, 0, stream>>>(W1, w1t);
  init_out_kernel<<<BATCH * QUANT / 256, 256, 0, stream>>>(out, b2);
  qhead_gemm_kernel<<<dim3(128, 128), 256, 0, stream>>>(xh, w1t, b1, W2, out);
}

// Round 3
// 904.611 us; speedup vs baseline: 1.6689x; 1.1762x over previous
//
#include <hip/hip_runtime.h>

#define HIDDEN 2048
#define QUANT  16
#define BATCH  8192
#define HALFD  1024

typedef _Float16 half8  __attribute__((ext_vector_type(8)));
typedef float    floatx16 __attribute__((ext_vector_type(16)));

__device__ __forceinline__ void load_lds16(const void* gptr, void* lptr) {
  __builtin_amdgcn_global_load_lds(
      (const __attribute__((address_space(1))) void*)gptr,
      (__attribute__((address_space(3))) void*)lptr, 16, 0, 0);
}

// exact-GELU via Abramowitz-Stegun 7.1.26 erf (|eps_erf| <= 1.5e-7)
__device__ __forceinline__ float gelu_exact(float v) {
  const float z  = 0.7071067811865476f * v;
  const float az = fabsf(z);
  const float t  = __builtin_amdgcn_rcpf(1.0f + 0.3275911f * az);
  const float p  = t * (0.254829592f +
                   t * (-0.284496736f +
                   t * (1.421413741f +
                   t * (-1.453152027f +
                   t * 1.061405429f))));
  float er = 1.0f - p * __expf(-az * az);
  er = copysignf(er, z);
  return 0.5f * v * (1.0f + er);
}

// ---- x fp32 -> fp16 ----
__global__ __launch_bounds__(256) void convert_x_kernel(const float* __restrict__ x,
                                                        _Float16* __restrict__ xh) {
  const int i = (blockIdx.x * 256 + threadIdx.x) * 8;
  const float4 a = *(const float4*)(x + i);
  const float4 b = *(const float4*)(x + i + 4);
  half8 h;
  h[0] = (_Float16)a.x; h[1] = (_Float16)a.y; h[2] = (_Float16)a.z; h[3] = (_Float16)a.w;
  h[4] = (_Float16)b.x; h[5] = (_Float16)b.y; h[6] = (_Float16)b.z; h[7] = (_Float16)b.w;
  *(half8*)(xh + i) = h;
}

// ---- W1 [Q][H][N] fp32 -> W1T [Q][N][H] fp16 ----
// 64(h) x 32(n) tiles; float4 loads, half8 (16B) coalesced stores.
// LDS row stride 33 floats: gather banks (8a+c+n) mod 32 -> 2-way max (free).
__global__ __launch_bounds__(256) void transpose_w1_kernel(const float* __restrict__ W1,
                                                           _Float16* __restrict__ W1T) {
  __shared__ float tile[64][33];
  const int q  = blockIdx.z;
  const int h0 = blockIdx.y * 64;
  const int n0 = blockIdx.x * 32;
  const float* src = W1 + (size_t)q * HIDDEN * HALFD;
  _Float16*    dst = W1T + (size_t)q * HALFD * HIDDEN;
  const int t  = threadIdx.x;
  const int lr = t >> 3;           // 0..31 h-row
  const int lc = (t & 7) * 4;      // n col group
  #pragma unroll
  for (int j = 0; j < 2; ++j) {
    const float4 v = *(const float4*)(src + (size_t)(h0 + lr + 32 * j) * HALFD + n0 + lc);
    tile[lr + 32 * j][lc + 0] = v.x;
    tile[lr + 32 * j][lc + 1] = v.y;
    tile[lr + 32 * j][lc + 2] = v.z;
    tile[lr + 32 * j][lc + 3] = v.w;
  }
  __syncthreads();
  const int sn = t >> 3;           // 0..31 n-row
  const int sh = (t & 7) * 8;      // h group
  half8 v;
  #pragma unroll
  for (int c = 0; c < 8; ++c) v[c] = (_Float16)tile[sh + c][sn];
  *(half8*)(dst + (size_t)(n0 + sn) * HIDDEN + h0 + sh) = v;
}

// ---- out[b][q] = b2[q] (atomics accumulate on top) ----
__global__ __launch_bounds__(256) void init_out_kernel(float* __restrict__ out,
                                                       const float* __restrict__ b2) {
  const int i = blockIdx.x * 256 + threadIdx.x;
  out[i] = b2[i & (QUANT - 1)];
}

// ---- fused GEMM + bias + GELU + W2-reduction ----
// Block tile 128(m) x 128(n), BK=64. 4 waves 2x2; each wave 64x64 via
// 2x2 frags of 32x32x16 f16 MFMA (2x operand-byte intensity vs 16x16x32).
__global__ __launch_bounds__(256, 4) void qhead_gemm_kernel(
    const _Float16* __restrict__ A,   // [BATCH][HIDDEN] fp16
    const _Float16* __restrict__ BT,  // [QUANT][HALFD][HIDDEN] fp16
    const float* __restrict__ b1,     // [QUANT][HALFD]
    const float* __restrict__ W2,     // [QUANT][HALFD]
    float* __restrict__ out) {        // [BATCH][QUANT]
  __shared__ _Float16 As[128 * 64];   // 16 KB
  __shared__ _Float16 Bs[128 * 64];   // 16 KB

  const int tid  = threadIdx.x;
  const int lane = tid & 63;
  const int wave = tid >> 6;
  const int wm = wave >> 1, wn = wave & 1;
  const int r31 = lane & 31, l5 = lane >> 5, lx = lane & 7;

  const int m0 = blockIdx.y << 7;
  const int q  = blockIdx.x >> 3;
  const int n0 = (blockIdx.x & 7) << 7;  // column base within head

  const _Float16* Ablk = A + (size_t)m0 * HIDDEN;
  const _Float16* Bblk = BT + ((size_t)q * HALFD + n0) * HIDDEN;

  // DMA staging: physical chunk c = tid + 256*i -> LDS bytes c*16 (wave-uniform
  // base + lane*16, contiguous). Chunk c holds logical (row r=c>>3, kgroup
  // g=(c&7)^(r&7)) -- XOR swizzle applied on the GLOBAL k-group index.
  const int row_t = tid >> 3;
  const int gx = (((tid & 7) ^ (row_t & 7)) << 3);
  const _Float16* agp = Ablk + (size_t)row_t * HIDDEN + gx;
  const _Float16* bgp = Bblk + (size_t)row_t * HIDDEN + gx;
  _Float16* alp = &As[tid * 8];
  _Float16* blp = &Bs[tid * 8];

  // frag base offsets (half-index): rows r = wX*64 + f*32 + r31, stride 64
  int aoff[2], boff[2];
  #pragma unroll
  for (int f = 0; f < 2; ++f) {
    aoff[f] = (wm * 64 + f * 32 + r31) * 64;
    boff[f] = (wn * 64 + f * 32 + r31) * 64;
  }

  floatx16 acc[2][2];
  #pragma unroll
  for (int mf = 0; mf < 2; ++mf)
    #pragma unroll
    for (int nf = 0; nf < 2; ++nf)
      #pragma unroll
      for (int i = 0; i < 16; ++i) acc[mf][nf][i] = 0.f;

  for (int kt = 0; kt < HIDDEN; kt += 64) {
    #pragma unroll
    for (int i = 0; i < 4; ++i)
      load_lds16(agp + (size_t)(i * 32) * HIDDEN + kt, alp + i * 2048);
    #pragma unroll
    for (int i = 0; i < 4; ++i)
      load_lds16(bgp + (size_t)(i * 32) * HIDDEN + kt, blp + i * 2048);
    __syncthreads();

    #pragma unroll
    for (int ks = 0; ks < 4; ++ks) {
      // lane wants kgroup w = ks*2 + l5 at swizzled position p = w ^ (r&7)
      const int p = (((ks << 1) | l5) ^ lx) << 3;
      half8 af[2], bf[2];
      #pragma unroll
      for (int mf = 0; mf < 2; ++mf) af[mf] = *(const half8*)&As[aoff[mf] + p];
      #pragma unroll
      for (int nf = 0; nf < 2; ++nf) bf[nf] = *(const half8*)&Bs[boff[nf] + p];
      #pragma unroll
      for (int mf = 0; mf < 2; ++mf)
        #pragma unroll
        for (int nf = 0; nf < 2; ++nf)
          acc[mf][nf] = __builtin_amdgcn_mfma_f32_32x32x16_f16(af[mf], bf[nf], acc[mf][nf], 0, 0, 0);
    }
    __syncthreads();
  }

  // ---- epilogue: bias + exact GELU + *W2, reduce over this wave's 64 columns ----
  // 32x32 C/D layout: col = lane&31, row = (reg&3) + 8*(reg>>2) + 4*(lane>>5)  [m74/m101]
  const int nbase = n0 + wn * 64;
  float rowsum[2][16];
  #pragma unroll
  for (int mf = 0; mf < 2; ++mf)
    #pragma unroll
    for (int r = 0; r < 16; ++r) rowsum[mf][r] = 0.f;

  #pragma unroll
  for (int nf = 0; nf < 2; ++nf) {
    const int ncol = nbase + nf * 32 + r31;
    const float b1v = b1[q * HALFD + ncol];
    const float w2v = W2[q * HALFD + ncol];
    #pragma unroll
    for (int mf = 0; mf < 2; ++mf)
      #pragma unroll
      for (int r = 0; r < 16; ++r)
        rowsum[mf][r] += gelu_exact(acc[mf][nf][r] + b1v) * w2v;
  }
  // butterfly-sum across the 32 column-lanes (low 5 lane bits)
  #pragma unroll
  for (int mf = 0; mf < 2; ++mf) {
    #pragma unroll
    for (int r = 0; r < 16; ++r) {
      float t = rowsum[mf][r];
      t += __shfl_xor(t, 1, 64);
      t += __shfl_xor(t, 2, 64);
      t += __shfl_xor(t, 4, 64);
      t += __shfl_xor(t, 8, 64);
      t += __shfl_xor(t, 16, 64);
      rowsum[mf][r] = t;
    }
  }
  if (r31 == 0) {
    #pragma unroll
    for (int mf = 0; mf < 2; ++mf) {
      const int mbase = m0 + wm * 64 + mf * 32 + 4 * l5;
      #pragma unroll
      for (int r = 0; r < 16; ++r) {
        const int mrow = mbase + (r & 3) + 8 * (r >> 2);
        atomicAdd(&out[(size_t)mrow * QUANT + q], rowsum[mf][r]);
      }
    }
  }
}

extern "C" void kernel_launch(void* const* d_in, const int* in_sizes, int n_in,
                              void* d_out, int out_size, void* d_ws, size_t ws_size,
                              hipStream_t stream) {
  const float* x  = (const float*)d_in[0];
  const float* W1 = (const float*)d_in[1];
  const float* b1 = (const float*)d_in[2];
  const float* W2 = (const float*)d_in[3];
  const float* b2 = (const float*)d_in[4];
  float* out = (float*)d_out;

  _Float16* xh  = (_Float16*)d_ws;                                   // 32 MB
  _Float16* w1t = (_Float16*)((char*)d_ws +
                  (size_t)BATCH * HIDDEN * sizeof(_Float16));        // 64 MB

  convert_x_kernel<<<BATCH * HIDDEN / (256 * 8), 256, 0, stream>>>(x, xh);
  transpose_w1_kernel<<<dim3(HALFD / 32, HIDDEN / 64, QUANT), 256, 0, stream>>>(W1, w1t);
  init_out_kernel<<<BATCH * QUANT / 256, 256, 0, stream>>>(out, b2);
  qhead_gemm_kernel<<<dim3(128, 64), 256, 0, stream>>>(xh, w1t, b1, W2, out);
}